// Round 6
// baseline (372.069 us; speedup 1.0000x reference)
//
#include <hip/hip_runtime.h>

// MoE forward: shared SwiGLU expert + top-2/8 routed SwiGLU experts + aux loss.
// R12 = R11 de-risked: ONLY the MFMA shape change (16x16x32 -> 32x32x16,
// 2382 vs 2075 TF ceiling, 2x FLOP/instr -> half the MFMA issue slots per
// phase at identical LDS traffic) on the byte-identical R10 control flow
// (runtime buf parity, proven barrier/vmcnt schedule; no lambda, no lgkm
// hint -- R11 bundled those and the container died). G/U interleave at 32-col
// granularity so each 32-wide n-frag is pure-G or pure-U (SwiGLU lane-local).
// A/B operand: row/col=lane&31, k=(lane>>5)*8+e. C/D: col=lane&31,
// row=(reg&3)+8*(reg>>2)+4*(lane>>5) (HW-verified layout).

typedef unsigned short u16;
typedef unsigned int   u32;
typedef short short8 __attribute__((ext_vector_type(8)));
typedef float f32x16 __attribute__((ext_vector_type(16)));

#define AS1 __attribute__((address_space(1)))
#define AS3 __attribute__((address_space(3)))

constexpr int T  = 8192;
constexpr int H  = 1024;
constexpr int E  = 8;
constexpr int D  = 512;
constexpr int DS = 1024;          // shared expert width
constexpr int PAIR_CAP  = 18432;  // 72*256 >= 16384 + 8*255, 256-aligned
constexpr int MT_ROUTED = 72;     // routed m-tiles (256 rows each)
constexpr int RB = 512;           // router blocks (16 tokens each)

constexpr int GU_ROUTED_BLKS = 4 * MT_ROUTED;   // 288 (N=1024 interleaved, BN=256)
constexpr int GU_SHARED_BLKS = 8 * (T / 256);   // 256 (N=2048 interleaved, BN=256)
constexpr int GU_BLKS  = GU_ROUTED_BLKS + GU_SHARED_BLKS;  // 544 (div by 8)
constexpr int DNR_BLKS = 4 * MT_ROUTED;         // 288 (N=1024, BN=256)
constexpr int DNS_BLKS = 4 * (T / 256);         // 128 (N=1024, BN=256)
constexpr int DN_BLKS  = DNR_BLKS + DNS_BLKS;   // 416 = 52*8

__device__ __forceinline__ u16 f2bf(float f){
  u32 u = __builtin_bit_cast(u32, f);
  u += 0x7fffu + ((u >> 16) & 1u);   // round-to-nearest-even
  return (u16)(u >> 16);
}
__device__ __forceinline__ float bf2f(u16 h){
  u32 u = ((u32)h) << 16;
  return __builtin_bit_cast(float, u);
}

// async global->LDS, 16B per lane. LDS dest = wave-uniform base + lane*16.
__device__ __forceinline__ void gl_lds16(const u16* g, u16* l){
  __builtin_amdgcn_global_load_lds((const AS1 void*)g, (AS3 void*)l, 16, 0, 0);
}

// s_waitcnt imm: vm[3:0] | exp=7<<4 | lgkm=15<<8 (vm high bits 0)
template<int N>
__device__ __forceinline__ void wait_vm(){ __builtin_amdgcn_s_waitcnt(0x0f70 | N); }

// RAW workgroup barrier, scheduling pinned on both sides.
__device__ __forceinline__ void bar(){
  __builtin_amdgcn_sched_barrier(0);
  __builtin_amdgcn_s_barrier();
  __builtin_amdgcn_sched_barrier(0);
}

// Fragment read offset (elems) for logical chunk c at a row with row&7==lane&7.
__device__ __forceinline__ int swz_off(int c, int lane){
  return ((c ^ (lane & 7)) * 8);
}

// Bijective chunked XCD remap (requires NWG % 8 == 0).
template<int NWG>
__device__ __forceinline__ int xcd_tau(int fid){
  return (fid & 7) * (NWG >> 3) + (fid >> 3);
}

// ---------------- router: logits -> softmax -> top2 + bf16 convert of x -----
__global__ void __launch_bounds__(256) router_kernel(
    const float* __restrict__ x, const float* __restrict__ Wr,
    u16* __restrict__ xb,
    int* __restrict__ topk_idx, float* __restrict__ topk_w,
    int* __restrict__ partial_hist, float* __restrict__ partial_probs)
{
  __shared__ int   hist_s[4][8];
  __shared__ float ps_s[4][8];
  int tid = threadIdx.x, lane = tid & 63, wv = tid >> 6;
  int   histl[8] = {0,0,0,0,0,0,0,0};
  float psl[8]   = {0.f,0.f,0.f,0.f,0.f,0.f,0.f,0.f};

  for (int it = 0; it < 4; ++it){
    int t = blockIdx.x * 16 + wv * 4 + it;
    const float4* xr = (const float4*)(x + (long)t * H);
    uint2* xbr = (uint2*)(xb + (long)t * H);
    float acc[8];
#pragma unroll
    for (int e = 0; e < 8; ++e) acc[e] = 0.f;
#pragma unroll
    for (int i = 0; i < 4; ++i){
      float4 xv = xr[i * 64 + lane];
      u32 lo = (u32)f2bf(xv.x) | ((u32)f2bf(xv.y) << 16);
      u32 hi = (u32)f2bf(xv.z) | ((u32)f2bf(xv.w) << 16);
      xbr[i * 64 + lane] = make_uint2(lo, hi);
      int h0 = i * 256 + lane * 4;
#pragma unroll
      for (int j = 0; j < 4; ++j){
        float xs = (j == 0) ? xv.x : (j == 1) ? xv.y : (j == 2) ? xv.z : xv.w;
        const float4* wr = (const float4*)(Wr + (long)(h0 + j) * E);
        float4 w0 = wr[0], w1 = wr[1];
        acc[0] += xs * w0.x; acc[1] += xs * w0.y; acc[2] += xs * w0.z; acc[3] += xs * w0.w;
        acc[4] += xs * w1.x; acc[5] += xs * w1.y; acc[6] += xs * w1.z; acc[7] += xs * w1.w;
      }
    }
#pragma unroll
    for (int off = 32; off >= 1; off >>= 1){
#pragma unroll
      for (int e = 0; e < 8; ++e) acc[e] += __shfl_xor(acc[e], off, 64);
    }
    if (lane == 0){
      float m = acc[0];
#pragma unroll
      for (int e = 1; e < 8; ++e) m = fmaxf(m, acc[e]);
      float p[8], s = 0.f;
#pragma unroll
      for (int e = 0; e < 8; ++e){ p[e] = __expf(acc[e] - m); s += p[e]; }
      float inv = 1.f / s;
#pragma unroll
      for (int e = 0; e < 8; ++e) psl[e] += p[e] * inv;
      int i1 = 0; float v1 = p[0];
#pragma unroll
      for (int e = 1; e < 8; ++e) if (p[e] > v1){ v1 = p[e]; i1 = e; }
      int i2 = -1; float v2 = -1.f;
#pragma unroll
      for (int e = 0; e < 8; ++e) if (e != i1 && p[e] > v2){ v2 = p[e]; i2 = e; }
      float rs = 1.f / (v1 + v2);
      topk_idx[2 * t] = i1; topk_idx[2 * t + 1] = i2;
      topk_w[2 * t] = v1 * rs; topk_w[2 * t + 1] = v2 * rs;
      histl[i1]++; histl[i2]++;
    }
  }
  if (lane == 0){
#pragma unroll
    for (int e = 0; e < 8; ++e){ hist_s[wv][e] = histl[e]; ps_s[wv][e] = psl[e]; }
  }
  __syncthreads();
  if (tid < 8){
    int hs = 0; float ps = 0.f;
#pragma unroll
    for (int w = 0; w < 4; ++w){ hs += hist_s[w][tid]; ps += ps_s[w][tid]; }
    partial_hist[blockIdx.x * 8 + tid]  = hs;
    partial_probs[blockIdx.x * 8 + tid] = ps;
  }
}

// ---------------- scan: 256-padded bases + per-block offsets + aux loss ------
__global__ void __launch_bounds__(64) scan_kernel(
    const int* __restrict__ partial_hist, const float* __restrict__ partial_probs,
    int* __restrict__ block_offset, float* __restrict__ out_aux,
    int* __restrict__ meta)
{
  __shared__ int   csum[8][8];
  __shared__ float cps[8][8];
  __shared__ int   cbase[8][8];
  __shared__ int   base_s[8];
  int tid = threadIdx.x, e = tid & 7, c = tid >> 3;
  int s = 0; float f = 0.f;
  for (int b = c * 64; b < c * 64 + 64; ++b){
    s += partial_hist[b * 8 + e]; f += partial_probs[b * 8 + e];
  }
  csum[c][e] = s; cps[c][e] = f;
  __syncthreads();
  if (tid < 8){
    int tot = 0;
    for (int cc = 0; cc < 8; ++cc){ cbase[cc][tid] = tot; tot += csum[cc][tid]; }
    csum[0][tid] = tot;            // column total (cbase already captured)
  }
  __syncthreads();
  if (tid == 0){
    int off = 0;
    for (int ee = 0; ee < 8; ++ee){ base_s[ee] = off; off += (csum[0][ee] + 255) & ~255; }
    meta[0] = off;                 // padded total (256-aligned)
    float a = 0.f;
    for (int ee = 0; ee < 8; ++ee){
      float ps = 0.f;
      for (int cc = 0; cc < 8; ++cc) ps += cps[cc][ee];
      float m = ps * (1.f / (float)T);
      a += m * m;
    }
    out_aux[0] = (float)E * a;
  }
  __syncthreads();
  int run = base_s[e] + cbase[c][e];
  for (int b = c * 64; b < c * 64 + 64; ++b){
    block_offset[b * 8 + e] = run;
    run += partial_hist[b * 8 + e];
  }
}

// ---------------- scatter: ballot-ranked, atomic-free ------------------------
__global__ void __launch_bounds__(64) scatter_kernel(
    const int* __restrict__ topk_idx, const float* __restrict__ topk_w,
    const int* __restrict__ block_offset,
    int* __restrict__ pair_token, int* __restrict__ pair_expert,
    float* __restrict__ pair_score, int* __restrict__ token_pos)
{
  int lane = threadIdx.x, b = blockIdx.x;
  if (lane >= 32) return;
  int idx = b * 32 + lane;
  int t = idx >> 1;
  int e = topk_idx[idx];
  float w = topk_w[idx];
  unsigned long long below = lane ? ((1ull << lane) - 1ull) : 0ull;
  int rank = 0, basee = 0;
#pragma unroll
  for (int ee = 0; ee < 8; ++ee){
    unsigned long long m = __ballot(e == ee);
    if (e == ee){ rank = __popcll(m & below); basee = block_offset[b * 8 + ee]; }
  }
  int pos = basee + rank;
  pair_token[pos] = t;
  pair_expert[pos] = e;
  pair_score[pos] = w;
  token_pos[idx] = pos;
}

// ---------------- all weight transposes in ONE launch ------------------------
// z: 0 Wsg->WsguT(G), 1 Wsu->WsguT(U), 2 Wsd->WsdT(plain),
//    [3,11) Wg->WguT(G), [11,19) Wu->WguT(U), [19,27) Wd->WdT(plain).
// 32-col interleave: dst row for src col c: G -> (c>>5)*64 + (c&31); U -> +32.
__global__ void __launch_bounds__(256) transpose_all(
    const float* __restrict__ Wsg, const float* __restrict__ Wsu, u16* __restrict__ WsguT,
    const float* __restrict__ Wsd, u16* __restrict__ WsdT,
    const float* __restrict__ Wg,  const float* __restrict__ Wu, u16* __restrict__ WguT,
    const float* __restrict__ Wd,  u16* __restrict__ WdT)
{
  __shared__ float tile[32][33];
  int z = blockIdx.z;
  const float* src; u16* dst; int R, C, itype;
  if (z < 3){
    R = 1024; C = 1024;
    if (z == 0){ src = Wsg; dst = WsguT; itype = 1; }
    else if (z == 1){ src = Wsu; dst = WsguT; itype = 2; }
    else { src = Wsd; dst = WsdT; itype = 0; }
  } else if (z < 19){
    R = 1024; C = 512;
    int p = z - 3;
    if (p < 8){ src = Wg + (long)p * R * C; dst = WguT + (long)p * (2 * D * H); itype = 1; }
    else      { src = Wu + (long)(p - 8) * R * C; dst = WguT + (long)(p - 8) * (2 * D * H); itype = 2; }
  } else {
    R = 512; C = 1024;
    int p = z - 19;
    src = Wd + (long)p * R * C; dst = WdT + (long)p * R * C; itype = 0;
  }
  int tx = threadIdx.x & 31, ty = threadIdx.x >> 5;
  int c = blockIdx.x * 32 + tx;
  int rb = blockIdx.y * 32;
  if (blockIdx.x * 32 >= C || rb >= R) return;
#pragma unroll
  for (int j = 0; j < 4; ++j)
    tile[ty + j * 8][tx] = src[(long)(rb + ty + j * 8) * C + c];
  __syncthreads();
#pragma unroll
  for (int j = 0; j < 4; ++j){
    int cc = blockIdx.x * 32 + ty + j * 8;
    int dr = (itype == 0) ? cc
           : (((cc >> 5) << 6) + (cc & 31) + ((itype == 2) ? 32 : 0));
    dst[(long)dr * R + rb + tx] = f2bf(tile[tx][ty + j * 8]);
  }
}

// ---------------- 256x256x64, 8-wave, 8-phase, 32x32x16-MFMA GEMM ------------
// Per-wave 128x64 output: 4 m-frags x 2 n-frags of 32x32, acc f32x16[4][2].
// LDS + staging + vmcnt schedule byte-identical to R10 (proven):
//   qd0: A-half0(t+1)  qd1: A-half1(t+1)  qd2: B-half0(t+2)  qd3: B-half1(t+2)
//   vmcnt(4) at qd3 (tail: vmcnt(0) at t>=NT-2).
struct HalfStage { const u16* p[2]; };

__device__ __forceinline__ void half_init(HalfStage& hs, const u16* __restrict__ gbase,
    int ld, int rowbase, const int* __restrict__ gather, int wave, int lane){
  int lr = lane >> 3, ch = lane & 7;
  int chs = (ch ^ lr) * 8;         // swizzled source chunk (LDS stays linear)
#pragma unroll
  for (int j = 0; j < 2; ++j){
    int row = (wave * 2 + j) * 8 + lr;          // 0..127
    int grow = gather ? gather[rowbase + row] : (rowbase + row);
    hs.p[j] = gbase + (long)grow * ld + chs;
  }
}

__device__ __forceinline__ void half_issue(const HalfStage& hs, int k0,
                                           u16* __restrict__ lds, int wave){
#pragma unroll
  for (int j = 0; j < 2; ++j)
    gl_lds16(hs.p[j] + k0, lds + (wave * 2 + j) * 512);
}

// EPI: 0 = gateup (32-col interleaved G/U, SwiGLU -> bf16 o_bf, ld o_ld)
//      1 = down_routed (scale by pair_score -> bf16 rout)
//      2 = down_shared (plain fp32 store to out; combine kernel adds routed)
template<int EPI>
__device__ __forceinline__ void gemm256(
    const u16* __restrict__ A, const u16* __restrict__ B, int K, int NT,
    const int* __restrict__ gather, int m0, int n0,
    u16* __restrict__ o_bf, int o_ld,
    const float* __restrict__ pair_score, float* __restrict__ out,
    u16* __restrict__ As, u16* __restrict__ Bs)
{
  int tid = threadIdx.x, lane = tid & 63, wave = tid >> 6;
  int wm = wave >> 2, wn = wave & 3;
  int l31 = lane & 31, kh = lane >> 5;

  HalfStage a0, a1, b0, b1;
  half_init(a0, A, K, m0,       gather, wave, lane);
  half_init(a1, A, K, m0 + 128, gather, wave, lane);
  half_init(b0, B, K, n0,       nullptr, wave, lane);
  half_init(b1, B, K, n0 + 128, nullptr, wave, lane);

  f32x16 acc[4][2];
#pragma unroll
  for (int i = 0; i < 4; ++i)
#pragma unroll
    for (int j = 0; j < 2; ++j)
#pragma unroll
      for (int r = 0; r < 16; ++r) acc[i][j][r] = 0.f;

  // prologue: tile0 fully + tile1 B halves; vmcnt(4) -> tile0 landed
  half_issue(b0, 0, Bs + 0 * 8192, wave);
  half_issue(b1, 0, Bs + 1 * 8192, wave);
  half_issue(a0, 0, As + 0 * 8192, wave);
  half_issue(a1, 0, As + 1 * 8192, wave);
  if (NT > 1){
    half_issue(b0, 64, Bs + 2 * 8192, wave);
    half_issue(b1, 64, Bs + 3 * 8192, wave);
    wait_vm<4>();
  } else {
    wait_vm<0>();
  }
  bar();

  int bhalf = wn >> 1, brow0 = (wn & 1) * 64;

#pragma unroll 1
  for (int t = 0; t < NT; ++t){
    int buf = t & 1, nbuf = buf ^ 1;
    const u16* Abase = As + (buf * 2 + wm) * 8192;
    const u16* Bbase = Bs + (buf * 2 + bhalf) * 8192;
    short8 bfr[4][2];
#pragma unroll
    for (int qd = 0; qd < 4; ++qd){
      // 1. ds-reads: A m-frag quadrant (4x b128); + all B frags (8) at qd==0
      short8 afr[4];
#pragma unroll
      for (int ks = 0; ks < 4; ++ks){
        int off = swz_off(ks * 2 + kh, lane);
        afr[ks] = *(const short8*)(Abase + (qd * 32 + l31) * 64 + off);
        if (qd == 0){
#pragma unroll
          for (int nf = 0; nf < 2; ++nf)
            bfr[ks][nf] = *(const short8*)(Bbase + (brow0 + nf * 32 + l31) * 64 + off);
        }
      }
      // 2. stage-issue per schedule
      if (qd == 0 && t + 1 < NT) half_issue(a0, (t + 1) * 64, As + (nbuf * 2 + 0) * 8192, wave);
      if (qd == 1 && t + 1 < NT) half_issue(a1, (t + 1) * 64, As + (nbuf * 2 + 1) * 8192, wave);
      if (qd == 2 && t + 2 < NT) half_issue(b0, (t + 2) * 64, Bs + (buf * 2 + 0) * 8192, wave);
      if (qd == 3 && t + 2 < NT) half_issue(b1, (t + 2) * 64, Bs + (buf * 2 + 1) * 8192, wave);
      // 3. raw barrier (pinned); compiler inserts fine-grained lgkm waits
      bar();
      // 4. MFMA cluster (8 x 32x32x16), T5 setprio
      __builtin_amdgcn_s_setprio(1);
#pragma unroll
      for (int ks = 0; ks < 4; ++ks)
#pragma unroll
        for (int nf = 0; nf < 2; ++nf)
          acc[qd][nf] = __builtin_amdgcn_mfma_f32_32x32x16_bf16(
              afr[ks], bfr[ks][nf], acc[qd][nf], 0, 0, 0);
      __builtin_amdgcn_s_setprio(0);
      // 5. counted vmcnt once per K-tile (tail: full drain)
      if (qd == 3){
        if (t + 2 < NT) wait_vm<4>(); else wait_vm<0>();
      }
      bar();
    }
  }

  int row0 = m0 + wm * 128;
  if constexpr (EPI == 0){
    int g0 = (n0 + wn * 64) >> 1;
#pragma unroll
    for (int mt = 0; mt < 4; ++mt)
#pragma unroll
      for (int r = 0; r < 16; ++r){
        int row = row0 + mt * 32 + (r & 3) + 8 * (r >> 2) + 4 * kh;
        float g = acc[mt][0][r], u = acc[mt][1][r];
        float h = g / (1.f + __expf(-g)) * u;
        o_bf[(long)row * o_ld + g0 + l31] = f2bf(h);
      }
  } else if constexpr (EPI == 1){
    int col0 = n0 + wn * 64;
#pragma unroll
    for (int mt = 0; mt < 4; ++mt)
#pragma unroll
      for (int r = 0; r < 16; ++r){
        int row = row0 + mt * 32 + (r & 3) + 8 * (r >> 2) + 4 * kh;
        float s = pair_score[row];
        long rbase = (long)row * H;
#pragma unroll
        for (int nf = 0; nf < 2; ++nf)
          o_bf[rbase + col0 + nf * 32 + l31] = f2bf(s * acc[mt][nf][r]);
      }
  } else {
    int col0 = n0 + wn * 64;
#pragma unroll
    for (int mt = 0; mt < 4; ++mt)
#pragma unroll
      for (int r = 0; r < 16; ++r){
        int row = row0 + mt * 32 + (r & 3) + 8 * (r >> 2) + 4 * kh;
        long o = (long)row * H;
#pragma unroll
        for (int nf = 0; nf < 2; ++nf)
          out[o + col0 + nf * 32 + l31] = acc[mt][nf][r];
      }
  }
}

// ---------------- GEMM kernels ----------------------------------------------
__global__ void __launch_bounds__(512, 2) gateup_fused(
    const u16* __restrict__ xb, const u16* __restrict__ WguT, u16* __restrict__ hr,
    const u16* __restrict__ WsguT, u16* __restrict__ hs,
    const int* __restrict__ pair_token, const int* __restrict__ pair_expert,
    const int* __restrict__ meta)
{
  __shared__ u16 As[4 * 8192];
  __shared__ u16 Bs[4 * 8192];
  int tau = xcd_tau<GU_BLKS>(blockIdx.x);
  if (tau < GU_ROUTED_BLKS){
    int mtile = tau >> 2, ntile = tau & 3;       // ntile-fastest
    int m0 = mtile * 256;
    if (m0 >= meta[0]) return;                   // all-dummy tile
    int e = pair_expert[m0];
    gemm256<0>(xb, WguT + (long)e * (2 * D * H), H, H / 64, pair_token,
               m0, ntile * 256, hr, D, nullptr, nullptr, As, Bs);
  } else {
    int sidx = tau - GU_ROUTED_BLKS;
    int mtile = sidx >> 3, ntile = sidx & 7;
    gemm256<0>(xb, WsguT, H, H / 64, nullptr,
               mtile * 256, ntile * 256, hs, DS, nullptr, nullptr, As, Bs);
  }
}

// fused down: routed tiles write rout (bf16, scaled); shared tiles write out
// (fp32, no combine). Independent -> one launch.
__global__ void __launch_bounds__(512, 2) down_fused(
    const u16* __restrict__ hr, const u16* __restrict__ WdT, u16* __restrict__ rout,
    const float* __restrict__ pair_score, const int* __restrict__ pair_expert,
    const int* __restrict__ meta,
    const u16* __restrict__ hs, const u16* __restrict__ WsdT,
    float* __restrict__ out)
{
  __shared__ u16 As[4 * 8192];
  __shared__ u16 Bs[4 * 8192];
  int tau = xcd_tau<DN_BLKS>(blockIdx.x);
  if (tau < DNR_BLKS){
    int mtile = tau >> 2, ntile = tau & 3;       // BN=256: 4 ntiles
    int m0 = mtile * 256;
    if (m0 >= meta[0]) return;
    int e = pair_expert[m0];
    gemm256<1>(hr, WdT + (long)e * (H * D), D, D / 64, nullptr,
               m0, ntile * 256, rout, H, pair_score, nullptr, As, Bs);
  } else {
    int sidx = tau - DNR_BLKS;
    int mtile = sidx >> 2, ntile = sidx & 3;     // BN=256: 4 ntiles
    gemm256<2>(hs, WsdT, DS, DS / 64, nullptr,
               mtile * 256, ntile * 256, nullptr, 0, nullptr, out, As, Bs);
  }
}

// ---------------- combine: out[t] += rout[p0] + rout[p1], coalesced ----------
__global__ void __launch_bounds__(256) combine_kernel(
    float* __restrict__ out, const u16* __restrict__ rout,
    const int* __restrict__ token_pos)
{
  int tid = threadIdx.x, lane = tid & 63, wv = tid >> 6;
#pragma unroll
  for (int it = 0; it < 4; ++it){
    int t = blockIdx.x * 16 + wv * 4 + it;
    int p0 = token_pos[2 * t], p1 = token_pos[2 * t + 1];
    const uint2* r0 = (const uint2*)(rout + (long)p0 * H);
    const uint2* r1 = (const uint2*)(rout + (long)p1 * H);
    float4* o = (float4*)(out + (long)t * H);
#pragma unroll
    for (int i = 0; i < 4; ++i){
      uint2 a = r0[i * 64 + lane], b = r1[i * 64 + lane];
      float4 v = o[i * 64 + lane];
      v.x += bf2f((u16)(a.x & 0xffff)) + bf2f((u16)(b.x & 0xffff));
      v.y += bf2f((u16)(a.x >> 16))    + bf2f((u16)(b.x >> 16));
      v.z += bf2f((u16)(a.y & 0xffff)) + bf2f((u16)(b.y & 0xffff));
      v.w += bf2f((u16)(a.y >> 16))    + bf2f((u16)(b.y >> 16));
      o[i * 64 + lane] = v;
    }
  }
}

// ---------------- launch -----------------------------------------------------
extern "C" void kernel_launch(void* const* d_in, const int* in_sizes, int n_in,
                              void* d_out, int out_size, void* d_ws, size_t ws_size,
                              hipStream_t stream)
{
  (void)in_sizes; (void)n_in; (void)out_size; (void)ws_size;
  const float* x   = (const float*)d_in[0];
  const float* Wr  = (const float*)d_in[1];
  const float* Wg  = (const float*)d_in[2];
  const float* Wu  = (const float*)d_in[3];
  const float* Wd  = (const float*)d_in[4];
  const float* Wsg = (const float*)d_in[5];
  const float* Wsu = (const float*)d_in[6];
  const float* Wsd = (const float*)d_in[7];
  float* out = (float*)d_out;

  char* ws = (char*)d_ws;
  size_t off = 0;
  auto alloc = [&](size_t bytes) -> void* {
    void* p = ws + off; off += (bytes + 255) & ~(size_t)255; return p;
  };
  u16* xb    = (u16*)alloc((size_t)T * H * 2);
  u16* WsguT = (u16*)alloc((size_t)2 * DS * H * 2);   // [2048][1024] interleaved-32
  u16* WsdT  = (u16*)alloc((size_t)H * DS * 2);
  u16* WguT  = (u16*)alloc((size_t)E * 2 * D * H * 2); // per-e [1024][1024] interleaved-32
  u16* WdT   = (u16*)alloc((size_t)E * H * D * 2);
  u16* hs    = (u16*)alloc((size_t)T * DS * 2);
  u16* hr    = (u16*)alloc((size_t)PAIR_CAP * D * 2);
  u16* rout  = (u16*)alloc((size_t)PAIR_CAP * H * 2);
  int*   topk_idx  = (int*)alloc((size_t)T * 2 * 4);
  float* topk_w    = (float*)alloc((size_t)T * 2 * 4);
  int*   token_pos = (int*)alloc((size_t)T * 2 * 4);
  int*   partial_hist  = (int*)alloc((size_t)RB * 8 * 4);
  float* partial_probs = (float*)alloc((size_t)RB * 8 * 4);
  int*   block_offset  = (int*)alloc((size_t)RB * 8 * 4);
  int*   meta          = (int*)alloc(256);
  // zero-initialized region (dummy pair slots must read as 0)
  char* zbase = ws + off;
  int*   pair_token  = (int*)alloc((size_t)PAIR_CAP * 4);
  int*   pair_expert = (int*)alloc((size_t)PAIR_CAP * 4);
  float* pair_score  = (float*)alloc((size_t)PAIR_CAP * 4);
  size_t zbytes = (size_t)((ws + off) - zbase);

  hipMemsetAsync(zbase, 0, zbytes, stream);

  transpose_all<<<dim3(32, 32, 27), 256, 0, stream>>>(
      Wsg, Wsu, WsguT, Wsd, WsdT, Wg, Wu, WguT, Wd, WdT);

  router_kernel<<<RB, 256, 0, stream>>>(x, Wr, xb, topk_idx, topk_w,
                                        partial_hist, partial_probs);
  scan_kernel<<<1, 64, 0, stream>>>(partial_hist, partial_probs, block_offset,
                                    out + (size_t)T * H, meta);
  scatter_kernel<<<RB, 64, 0, stream>>>(topk_idx, topk_w, block_offset,
                                        pair_token, pair_expert, pair_score, token_pos);

  // fused gate+up (interleaved G/U): routed -> hr, shared -> hs
  gateup_fused<<<GU_BLKS, 512, 0, stream>>>(
      xb, WguT, hr, WsguT, hs, pair_token, pair_expert, meta);

  // fused down: routed -> rout (bf16, scaled) || shared -> out (fp32)
  down_fused<<<DN_BLKS, 512, 0, stream>>>(
      hr, WdT, rout, pair_score, pair_expert, meta, hs, WsdT, out);

  // coalesced combine: out[t] += rout[p0] + rout[p1]
  combine_kernel<<<T / 16, 256, 0, stream>>>(out, rout, token_pos);
}

// Round 8
// 367.077 us; speedup vs baseline: 1.0136x; 1.0136x over previous
//
#include <hip/hip_runtime.h>

// MoE forward: shared SwiGLU expert + top-2/8 routed SwiGLU experts + aux loss.
// R15 = R13 with the compile fix (inline the A-row expression; helper had been
// declared after use). Single-variable experiment vs R10: drop sched_barrier(0)
// pins at phase barriers (keep raw s_barrier), one pin only after each
// tile-boundary (post-vmcnt) barrier. Rationale: R12 falsified
// MFMA-issue/HBM/L2/conflict theories; m201 hits 62% MfmaUtil with identical
// geometry and NO pins on plain ds_reads -- our pins forbid the compiler from
// overlapping ds_read latency + stage-issue under the previous MFMA cluster.
// Cross-tile read hoisting past the vmcnt landing wait is the only hazard ->
// one pin after the tile-boundary barrier. Everything else = R10.

typedef unsigned short u16;
typedef unsigned int   u32;
typedef short short8 __attribute__((ext_vector_type(8)));
typedef float f32x4  __attribute__((ext_vector_type(4)));

#define AS1 __attribute__((address_space(1)))
#define AS3 __attribute__((address_space(3)))

constexpr int T  = 8192;
constexpr int H  = 1024;
constexpr int E  = 8;
constexpr int D  = 512;
constexpr int DS = 1024;          // shared expert width
constexpr int PAIR_CAP  = 18432;  // 72*256 >= 16384 + 8*255, 256-aligned
constexpr int MT_ROUTED = 72;     // routed m-tiles (256 rows each)
constexpr int RB = 512;           // router blocks (16 tokens each)

constexpr int GU_ROUTED_BLKS = 4 * MT_ROUTED;   // 288 (N=1024 interleaved, BN=256)
constexpr int GU_SHARED_BLKS = 8 * (T / 256);   // 256 (N=2048 interleaved, BN=256)
constexpr int GU_BLKS  = GU_ROUTED_BLKS + GU_SHARED_BLKS;  // 544 (div by 8)
constexpr int DNR_BLKS = 4 * MT_ROUTED;         // 288 (N=1024, BN=256)
constexpr int DNS_BLKS = 4 * (T / 256);         // 128 (N=1024, BN=256)
constexpr int DN_BLKS  = DNR_BLKS + DNS_BLKS;   // 416 = 52*8

__device__ __forceinline__ u16 f2bf(float f){
  u32 u = __builtin_bit_cast(u32, f);
  u += 0x7fffu + ((u >> 16) & 1u);   // round-to-nearest-even
  return (u16)(u >> 16);
}
__device__ __forceinline__ float bf2f(u16 h){
  u32 u = ((u32)h) << 16;
  return __builtin_bit_cast(float, u);
}

// async global->LDS, 16B per lane. LDS dest = wave-uniform base + lane*16.
__device__ __forceinline__ void gl_lds16(const u16* g, u16* l){
  __builtin_amdgcn_global_load_lds((const AS1 void*)g, (AS3 void*)l, 16, 0, 0);
}

// s_waitcnt imm: vm[3:0] | exp=7<<4 | lgkm=15<<8 (vm high bits 0)
template<int N>
__device__ __forceinline__ void wait_vm(){ __builtin_amdgcn_s_waitcnt(0x0f70 | N); }

// RAW phase barrier: no scheduling pin -- let the compiler overlap ds_reads /
// stage-issue with MFMAs across it (same-buffer within a tile: safe).
__device__ __forceinline__ void bar_raw(){
  __builtin_amdgcn_s_barrier();
}
// Tile-boundary barrier: pin AFTER, so next tile's buffer reads cannot hoist
// above the vmcnt landing wait (compiler doesn't model global_load_lds async).
__device__ __forceinline__ void bar_pin(){
  __builtin_amdgcn_s_barrier();
  __builtin_amdgcn_sched_barrier(0);
}

// Fragment read offset (elems) for logical chunk c at a row with row&7==lane&7.
__device__ __forceinline__ int swz_off(int c, int lane){
  return ((c ^ (lane & 7)) * 8);
}

// Bijective chunked XCD remap (requires NWG % 8 == 0).
template<int NWG>
__device__ __forceinline__ int xcd_tau(int fid){
  return (fid & 7) * (NWG >> 3) + (fid >> 3);
}

// ---------------- router: logits -> softmax -> top2 + bf16 convert of x -----
__global__ void __launch_bounds__(256) router_kernel(
    const float* __restrict__ x, const float* __restrict__ Wr,
    u16* __restrict__ xb,
    int* __restrict__ topk_idx, float* __restrict__ topk_w,
    int* __restrict__ partial_hist, float* __restrict__ partial_probs)
{
  __shared__ int   hist_s[4][8];
  __shared__ float ps_s[4][8];
  int tid = threadIdx.x, lane = tid & 63, wv = tid >> 6;
  int   histl[8] = {0,0,0,0,0,0,0,0};
  float psl[8]   = {0.f,0.f,0.f,0.f,0.f,0.f,0.f,0.f};

  for (int it = 0; it < 4; ++it){
    int t = blockIdx.x * 16 + wv * 4 + it;
    const float4* xr = (const float4*)(x + (long)t * H);
    uint2* xbr = (uint2*)(xb + (long)t * H);
    float acc[8];
#pragma unroll
    for (int e = 0; e < 8; ++e) acc[e] = 0.f;
#pragma unroll
    for (int i = 0; i < 4; ++i){
      float4 xv = xr[i * 64 + lane];
      u32 lo = (u32)f2bf(xv.x) | ((u32)f2bf(xv.y) << 16);
      u32 hi = (u32)f2bf(xv.z) | ((u32)f2bf(xv.w) << 16);
      xbr[i * 64 + lane] = make_uint2(lo, hi);
      int h0 = i * 256 + lane * 4;
#pragma unroll
      for (int j = 0; j < 4; ++j){
        float xs = (j == 0) ? xv.x : (j == 1) ? xv.y : (j == 2) ? xv.z : xv.w;
        const float4* wr = (const float4*)(Wr + (long)(h0 + j) * E);
        float4 w0 = wr[0], w1 = wr[1];
        acc[0] += xs * w0.x; acc[1] += xs * w0.y; acc[2] += xs * w0.z; acc[3] += xs * w0.w;
        acc[4] += xs * w1.x; acc[5] += xs * w1.y; acc[6] += xs * w1.z; acc[7] += xs * w1.w;
      }
    }
#pragma unroll
    for (int off = 32; off >= 1; off >>= 1){
#pragma unroll
      for (int e = 0; e < 8; ++e) acc[e] += __shfl_xor(acc[e], off, 64);
    }
    if (lane == 0){
      float m = acc[0];
#pragma unroll
      for (int e = 1; e < 8; ++e) m = fmaxf(m, acc[e]);
      float p[8], s = 0.f;
#pragma unroll
      for (int e = 0; e < 8; ++e){ p[e] = __expf(acc[e] - m); s += p[e]; }
      float inv = 1.f / s;
#pragma unroll
      for (int e = 0; e < 8; ++e) psl[e] += p[e] * inv;
      int i1 = 0; float v1 = p[0];
#pragma unroll
      for (int e = 1; e < 8; ++e) if (p[e] > v1){ v1 = p[e]; i1 = e; }
      int i2 = -1; float v2 = -1.f;
#pragma unroll
      for (int e = 0; e < 8; ++e) if (e != i1 && p[e] > v2){ v2 = p[e]; i2 = e; }
      float rs = 1.f / (v1 + v2);
      topk_idx[2 * t] = i1; topk_idx[2 * t + 1] = i2;
      topk_w[2 * t] = v1 * rs; topk_w[2 * t + 1] = v2 * rs;
      histl[i1]++; histl[i2]++;
    }
  }
  if (lane == 0){
#pragma unroll
    for (int e = 0; e < 8; ++e){ hist_s[wv][e] = histl[e]; ps_s[wv][e] = psl[e]; }
  }
  __syncthreads();
  if (tid < 8){
    int hs = 0; float ps = 0.f;
#pragma unroll
    for (int w = 0; w < 4; ++w){ hs += hist_s[w][tid]; ps += ps_s[w][tid]; }
    partial_hist[blockIdx.x * 8 + tid]  = hs;
    partial_probs[blockIdx.x * 8 + tid] = ps;
  }
}

// ---------------- scan: 256-padded bases + per-block offsets + aux loss ------
__global__ void __launch_bounds__(64) scan_kernel(
    const int* __restrict__ partial_hist, const float* __restrict__ partial_probs,
    int* __restrict__ block_offset, float* __restrict__ out_aux,
    int* __restrict__ meta)
{
  __shared__ int   csum[8][8];
  __shared__ float cps[8][8];
  __shared__ int   cbase[8][8];
  __shared__ int   base_s[8];
  int tid = threadIdx.x, e = tid & 7, c = tid >> 3;
  int s = 0; float f = 0.f;
  for (int b = c * 64; b < c * 64 + 64; ++b){
    s += partial_hist[b * 8 + e]; f += partial_probs[b * 8 + e];
  }
  csum[c][e] = s; cps[c][e] = f;
  __syncthreads();
  if (tid < 8){
    int tot = 0;
    for (int cc = 0; cc < 8; ++cc){ cbase[cc][tid] = tot; tot += csum[cc][tid]; }
    csum[0][tid] = tot;            // column total (cbase already captured)
  }
  __syncthreads();
  if (tid == 0){
    int off = 0;
    for (int ee = 0; ee < 8; ++ee){ base_s[ee] = off; off += (csum[0][ee] + 255) & ~255; }
    meta[0] = off;                 // padded total (256-aligned)
    float a = 0.f;
    for (int ee = 0; ee < 8; ++ee){
      float ps = 0.f;
      for (int cc = 0; cc < 8; ++cc) ps += cps[cc][ee];
      float m = ps * (1.f / (float)T);
      a += m * m;
    }
    out_aux[0] = (float)E * a;
  }
  __syncthreads();
  int run = base_s[e] + cbase[c][e];
  for (int b = c * 64; b < c * 64 + 64; ++b){
    block_offset[b * 8 + e] = run;
    run += partial_hist[b * 8 + e];
  }
}

// ---------------- scatter: ballot-ranked, atomic-free ------------------------
__global__ void __launch_bounds__(64) scatter_kernel(
    const int* __restrict__ topk_idx, const float* __restrict__ topk_w,
    const int* __restrict__ block_offset,
    int* __restrict__ pair_token, int* __restrict__ pair_expert,
    float* __restrict__ pair_score, int* __restrict__ token_pos)
{
  int lane = threadIdx.x, b = blockIdx.x;
  if (lane >= 32) return;
  int idx = b * 32 + lane;
  int t = idx >> 1;
  int e = topk_idx[idx];
  float w = topk_w[idx];
  unsigned long long below = lane ? ((1ull << lane) - 1ull) : 0ull;
  int rank = 0, basee = 0;
#pragma unroll
  for (int ee = 0; ee < 8; ++ee){
    unsigned long long m = __ballot(e == ee);
    if (e == ee){ rank = __popcll(m & below); basee = block_offset[b * 8 + ee]; }
  }
  int pos = basee + rank;
  pair_token[pos] = t;
  pair_expert[pos] = e;
  pair_score[pos] = w;
  token_pos[idx] = pos;
}

// ---------------- all weight transposes in ONE launch ------------------------
// z: 0 Wsg->WsguT(lo), 1 Wsu->WsguT(hi), 2 Wsd->WsdT(plain),
//    [3,11) Wg->WguT(lo), [11,19) Wu->WguT(hi), [19,27) Wd->WdT(plain).
// 16-col interleave: dst row for src col c: lo -> (c>>4)*32 + (c&15); hi -> +16.
__global__ void __launch_bounds__(256) transpose_all(
    const float* __restrict__ Wsg, const float* __restrict__ Wsu, u16* __restrict__ WsguT,
    const float* __restrict__ Wsd, u16* __restrict__ WsdT,
    const float* __restrict__ Wg,  const float* __restrict__ Wu, u16* __restrict__ WguT,
    const float* __restrict__ Wd,  u16* __restrict__ WdT)
{
  __shared__ float tile[32][33];
  int z = blockIdx.z;
  const float* src; u16* dst; int R, C, itype;
  if (z < 3){
    R = 1024; C = 1024;
    if (z == 0){ src = Wsg; dst = WsguT; itype = 1; }
    else if (z == 1){ src = Wsu; dst = WsguT; itype = 2; }
    else { src = Wsd; dst = WsdT; itype = 0; }
  } else if (z < 19){
    R = 1024; C = 512;
    int p = z - 3;
    if (p < 8){ src = Wg + (long)p * R * C; dst = WguT + (long)p * (2 * D * H); itype = 1; }
    else      { src = Wu + (long)(p - 8) * R * C; dst = WguT + (long)(p - 8) * (2 * D * H); itype = 2; }
  } else {
    R = 512; C = 1024;
    int p = z - 19;
    src = Wd + (long)p * R * C; dst = WdT + (long)p * R * C; itype = 0;
  }
  int tx = threadIdx.x & 31, ty = threadIdx.x >> 5;
  int c = blockIdx.x * 32 + tx;
  int rb = blockIdx.y * 32;
  if (blockIdx.x * 32 >= C || rb >= R) return;
#pragma unroll
  for (int j = 0; j < 4; ++j)
    tile[ty + j * 8][tx] = src[(long)(rb + ty + j * 8) * C + c];
  __syncthreads();
#pragma unroll
  for (int j = 0; j < 4; ++j){
    int cc = blockIdx.x * 32 + ty + j * 8;
    int dr = (itype == 0) ? cc : ((cc >> 4) * 32 + (cc & 15) + ((itype == 2) ? 16 : 0));
    dst[(long)dr * R + rb + tx] = f2bf(tile[tx][ty + j * 8]);
  }
}

// ---------------- 256x256x64, 8-wave, 8-phase GEMM template ------------------
// Per-wave 128x64 output (wm in 2, wn in 4). LDS: A[2buf][2half][128][64] +
// B same = 128 KiB. Stage schedule per K-tile t (4 quadrant phases qd):
//   qd0: A-half0(t+1)  qd1: A-half1(t+1)  qd2: B-half0(t+2)  qd3: B-half1(t+2)
//   vmcnt(4) at qd3 -> A(t+1)/B(t+1) landed, only B(t+2) in flight.
// Tail: at t >= NT-2 no B(t+2) issued -> vmcnt(0).
struct HalfStage { const u16* p[2]; };

__device__ __forceinline__ void half_init(HalfStage& hs, const u16* __restrict__ gbase,
    int ld, int rowbase, const int* __restrict__ gather, int wave, int lane){
  int lr = lane >> 3, ch = lane & 7;
  int chs = (ch ^ lr) * 8;         // swizzled source chunk (LDS stays linear)
#pragma unroll
  for (int j = 0; j < 2; ++j){
    int row = (wave * 2 + j) * 8 + lr;          // 0..127
    int grow = gather ? gather[rowbase + row] : (rowbase + row);
    hs.p[j] = gbase + (long)grow * ld + chs;
  }
}

__device__ __forceinline__ void half_issue(const HalfStage& hs, int k0,
                                           u16* __restrict__ lds, int wave){
#pragma unroll
  for (int j = 0; j < 2; ++j)
    gl_lds16(hs.p[j] + k0, lds + (wave * 2 + j) * 512);
}

// EPI: 0 = gateup (interleaved G/U, SwiGLU -> bf16 o_bf, ld o_ld)
//      1 = down_routed (scale by pair_score -> bf16 rout)
//      2 = down_shared (plain fp32 store to out; combine kernel adds routed)
template<int EPI>
__device__ __forceinline__ void gemm256(
    const u16* __restrict__ A, const u16* __restrict__ B, int K, int NT,
    const int* __restrict__ gather, int m0, int n0,
    u16* __restrict__ o_bf, int o_ld,
    const float* __restrict__ pair_score, float* __restrict__ out,
    u16* __restrict__ As, u16* __restrict__ Bs)
{
  int tid = threadIdx.x, lane = tid & 63, wave = tid >> 6;
  int wm = wave >> 2, wn = wave & 3;
  int rl = lane & 15, q = lane >> 4;

  HalfStage a0, a1, b0, b1;
  half_init(a0, A, K, m0,       gather, wave, lane);
  half_init(a1, A, K, m0 + 128, gather, wave, lane);
  half_init(b0, B, K, n0,       nullptr, wave, lane);
  half_init(b1, B, K, n0 + 128, nullptr, wave, lane);

  f32x4 acc[8][4];
#pragma unroll
  for (int i = 0; i < 8; ++i)
#pragma unroll
    for (int j = 0; j < 4; ++j)
#pragma unroll
      for (int r = 0; r < 4; ++r) acc[i][j][r] = 0.f;

  // prologue: tile0 fully + tile1 B halves; vmcnt(4) -> tile0 landed
  half_issue(b0, 0, Bs + 0 * 8192, wave);
  half_issue(b1, 0, Bs + 1 * 8192, wave);
  half_issue(a0, 0, As + 0 * 8192, wave);
  half_issue(a1, 0, As + 1 * 8192, wave);
  if (NT > 1){
    half_issue(b0, 64, Bs + 2 * 8192, wave);
    half_issue(b1, 64, Bs + 3 * 8192, wave);
    wait_vm<4>();
  } else {
    wait_vm<0>();
  }
  bar_pin();

  int bhalf = wn >> 1, brow0 = (wn & 1) * 64;

#pragma unroll 1
  for (int t = 0; t < NT; ++t){
    int buf = t & 1, nbuf = buf ^ 1;
    const u16* Abase = As + (buf * 2 + wm) * 8192;
    const u16* Bbase = Bs + (buf * 2 + bhalf) * 8192;
    short8 bfr[2][4];
#pragma unroll
    for (int qd = 0; qd < 4; ++qd){
      // 1. ds-reads: A quadrant (4x b128); + all B frags (8x b128) at qd==0
      short8 afr[2][2];
#pragma unroll
      for (int ks = 0; ks < 2; ++ks){
        int off = swz_off(ks * 4 + q, lane);
#pragma unroll
        for (int m = 0; m < 2; ++m)
          afr[ks][m] = *(const short8*)(Abase + (qd * 32 + m * 16 + rl) * 64 + off);
        if (qd == 0){
#pragma unroll
          for (int n = 0; n < 4; ++n)
            bfr[ks][n] = *(const short8*)(Bbase + (brow0 + n * 16 + rl) * 64 + off);
        }
      }
      // 2. stage-issue per schedule
      if (qd == 0 && t + 1 < NT) half_issue(a0, (t + 1) * 64, As + (nbuf * 2 + 0) * 8192, wave);
      if (qd == 1 && t + 1 < NT) half_issue(a1, (t + 1) * 64, As + (nbuf * 2 + 1) * 8192, wave);
      if (qd == 2 && t + 2 < NT) half_issue(b0, (t + 2) * 64, Bs + (buf * 2 + 0) * 8192, wave);
      if (qd == 3 && t + 2 < NT) half_issue(b1, (t + 2) * 64, Bs + (buf * 2 + 1) * 8192, wave);
      // 3. raw barrier (unpinned: compiler may overlap same-tile reads/MFMA)
      bar_raw();
      // 4. MFMA cluster (16), T5 setprio
      __builtin_amdgcn_s_setprio(1);
#pragma unroll
      for (int ks = 0; ks < 2; ++ks)
#pragma unroll
        for (int m = 0; m < 2; ++m)
#pragma unroll
          for (int n = 0; n < 4; ++n)
            acc[qd * 2 + m][n] = __builtin_amdgcn_mfma_f32_16x16x32_bf16(
                afr[ks][m], bfr[ks][n], acc[qd * 2 + m][n], 0, 0, 0);
      __builtin_amdgcn_s_setprio(0);
      // 5. counted vmcnt once per K-tile; tile-boundary barrier is pinned
      if (qd == 3){
        if (t + 2 < NT) wait_vm<4>(); else wait_vm<0>();
        bar_pin();
      } else {
        bar_raw();
      }
    }
  }

  int row0 = m0 + wm * 128;
  if constexpr (EPI == 0){
    int hcol0 = (n0 >> 1) + wn * 32;
#pragma unroll
    for (int mt = 0; mt < 8; ++mt)
#pragma unroll
      for (int ntp = 0; ntp < 2; ++ntp)
#pragma unroll
        for (int r = 0; r < 4; ++r){
          int row = row0 + mt * 16 + q * 4 + r;
          int col = hcol0 + ntp * 16 + rl;
          float g = acc[mt][2 * ntp][r], u = acc[mt][2 * ntp + 1][r];
          float h = g / (1.f + __expf(-g)) * u;
          o_bf[(long)row * o_ld + col] = f2bf(h);
        }
  } else if constexpr (EPI == 1){
    int col0 = n0 + wn * 64;
#pragma unroll
    for (int mt = 0; mt < 8; ++mt)
#pragma unroll
      for (int r = 0; r < 4; ++r){
        int row = row0 + mt * 16 + q * 4 + r;
        float s = pair_score[row];
        long rbase = (long)row * H;
#pragma unroll
        for (int n = 0; n < 4; ++n){
          int col = col0 + n * 16 + rl;
          o_bf[rbase + col] = f2bf(s * acc[mt][n][r]);
        }
      }
  } else {
    int col0 = n0 + wn * 64;
#pragma unroll
    for (int mt = 0; mt < 8; ++mt)
#pragma unroll
      for (int r = 0; r < 4; ++r){
        int row = row0 + mt * 16 + q * 4 + r;
        long o = (long)row * H;
#pragma unroll
        for (int n = 0; n < 4; ++n){
          int col = col0 + n * 16 + rl;
          out[o + col] = acc[mt][n][r];
        }
      }
  }
}

// ---------------- GEMM kernels ----------------------------------------------
__global__ void __launch_bounds__(512, 2) gateup_fused(
    const u16* __restrict__ xb, const u16* __restrict__ WguT, u16* __restrict__ hr,
    const u16* __restrict__ WsguT, u16* __restrict__ hs,
    const int* __restrict__ pair_token, const int* __restrict__ pair_expert,
    const int* __restrict__ meta)
{
  __shared__ u16 As[4 * 8192];
  __shared__ u16 Bs[4 * 8192];
  int tau = xcd_tau<GU_BLKS>(blockIdx.x);
  if (tau < GU_ROUTED_BLKS){
    int mtile = tau >> 2, ntile = tau & 3;       // ntile-fastest
    int m0 = mtile * 256;
    if (m0 >= meta[0]) return;                   // all-dummy tile
    int e = pair_expert[m0];
    gemm256<0>(xb, WguT + (long)e * (2 * D * H), H, H / 64, pair_token,
               m0, ntile * 256, hr, D, nullptr, nullptr, As, Bs);
  } else {
    int sidx = tau - GU_ROUTED_BLKS;
    int mtile = sidx >> 3, ntile = sidx & 7;
    gemm256<0>(xb, WsguT, H, H / 64, nullptr,
               mtile * 256, ntile * 256, hs, DS, nullptr, nullptr, As, Bs);
  }
}

// fused down: routed tiles write rout (bf16, scaled); shared tiles write out
// (fp32, no combine). Independent -> one launch.
__global__ void __launch_bounds__(512, 2) down_fused(
    const u16* __restrict__ hr, const u16* __restrict__ WdT, u16* __restrict__ rout,
    const float* __restrict__ pair_score, const int* __restrict__ pair_expert,
    const int* __restrict__ meta,
    const u16* __restrict__ hs, const u16* __restrict__ WsdT,
    float* __restrict__ out)
{
  __shared__ u16 As[4 * 8192];
  __shared__ u16 Bs[4 * 8192];
  int tau = xcd_tau<DN_BLKS>(blockIdx.x);
  if (tau < DNR_BLKS){
    int mtile = tau >> 2, ntile = tau & 3;       // BN=256: 4 ntiles
    int m0 = mtile * 256;
    if (m0 >= meta[0]) return;
    int e = pair_expert[m0];
    gemm256<1>(hr, WdT + (long)e * (H * D), D, D / 64, nullptr,
               m0, ntile * 256, rout, H, pair_score, nullptr, As, Bs);
  } else {
    int sidx = tau - DNR_BLKS;
    int mtile = sidx >> 2, ntile = sidx & 3;     // BN=256: 4 ntiles
    gemm256<2>(hs, WsdT, DS, DS / 64, nullptr,
               mtile * 256, ntile * 256, nullptr, 0, nullptr, out, As, Bs);
  }
}

// ---------------- combine: out[t] += rout[p0] + rout[p1], coalesced ----------
__global__ void __launch_bounds__(256) combine_kernel(
    float* __restrict__ out, const u16* __restrict__ rout,
    const int* __restrict__ token_pos)
{
  int tid = threadIdx.x, lane = tid & 63, wv = tid >> 6;
#pragma unroll
  for (int it = 0; it < 4; ++it){
    int t = blockIdx.x * 16 + wv * 4 + it;
    int p0 = token_pos[2 * t], p1 = token_pos[2 * t + 1];
    const uint2* r0 = (const uint2*)(rout + (long)p0 * H);
    const uint2* r1 = (const uint2*)(rout + (long)p1 * H);
    float4* o = (float4*)(out + (long)t * H);
#pragma unroll
    for (int i = 0; i < 4; ++i){
      uint2 a = r0[i * 64 + lane], b = r1[i * 64 + lane];
      float4 v = o[i * 64 + lane];
      v.x += bf2f((u16)(a.x & 0xffff)) + bf2f((u16)(b.x & 0xffff));
      v.y += bf2f((u16)(a.x >> 16))    + bf2f((u16)(b.x >> 16));
      v.z += bf2f((u16)(a.y & 0xffff)) + bf2f((u16)(b.y & 0xffff));
      v.w += bf2f((u16)(a.y >> 16))    + bf2f((u16)(b.y >> 16));
      o[i * 64 + lane] = v;
    }
  }
}

// ---------------- launch -----------------------------------------------------
extern "C" void kernel_launch(void* const* d_in, const int* in_sizes, int n_in,
                              void* d_out, int out_size, void* d_ws, size_t ws_size,
                              hipStream_t stream)
{
  (void)in_sizes; (void)n_in; (void)out_size; (void)ws_size;
  const float* x   = (const float*)d_in[0];
  const float* Wr  = (const float*)d_in[1];
  const float* Wg  = (const float*)d_in[2];
  const float* Wu  = (const float*)d_in[3];
  const float* Wd  = (const float*)d_in[4];
  const float* Wsg = (const float*)d_in[5];
  const float* Wsu = (const float*)d_in[6];
  const float* Wsd = (const float*)d_in[7];
  float* out = (float*)d_out;

  char* ws = (char*)d_ws;
  size_t off = 0;
  auto alloc = [&](size_t bytes) -> void* {
    void* p = ws + off; off += (bytes + 255) & ~(size_t)255; return p;
  };
  u16* xb    = (u16*)alloc((size_t)T * H * 2);
  u16* WsguT = (u16*)alloc((size_t)2 * DS * H * 2);   // [2048][1024] interleaved
  u16* WsdT  = (u16*)alloc((size_t)H * DS * 2);
  u16* WguT  = (u16*)alloc((size_t)E * 2 * D * H * 2); // per-e [1024][1024] interleaved
  u16* WdT   = (u16*)alloc((size_t)E * H * D * 2);
  u16* hs    = (u16*)alloc((size_t)T * DS * 2);
  u16* hr    = (u16*)alloc((size_t)PAIR_CAP * D * 2);
  u16* rout  = (u16*)alloc((size_t)PAIR_CAP * H * 2);
  int*   topk_idx  = (int*)alloc((size_t)T * 2 * 4);
  float* topk_w    = (float*)alloc((size_t)T * 2 * 4);
  int*   token_pos = (int*)alloc((size_t)T * 2 * 4);
  int*   partial_hist  = (int*)alloc((size_t)RB * 8 * 4);
  float* partial_probs = (float*)alloc((size_t)RB * 8 * 4);
  int*   block_offset  = (int*)alloc((size_t)RB * 8 * 4);
  int*   meta          = (int*)alloc(256);
  // zero-initialized region (dummy pair slots must read as 0)
  char* zbase = ws + off;
  int*   pair_token  = (int*)alloc((size_t)PAIR_CAP * 4);
  int*   pair_expert = (int*)alloc((size_t)PAIR_CAP * 4);
  float* pair_score  = (float*)alloc((size_t)PAIR_CAP * 4);
  size_t zbytes = (size_t)((ws + off) - zbase);

  (void)hipMemsetAsync(zbase, 0, zbytes, stream);

  transpose_all<<<dim3(32, 32, 27), 256, 0, stream>>>(
      Wsg, Wsu, WsguT, Wsd, WsdT, Wg, Wu, WguT, Wd, WdT);

  router_kernel<<<RB, 256, 0, stream>>>(x, Wr, xb, topk_idx, topk_w,
                                        partial_hist, partial_probs);
  scan_kernel<<<1, 64, 0, stream>>>(partial_hist, partial_probs, block_offset,
                                    out + (size_t)T * H, meta);
  scatter_kernel<<<RB, 64, 0, stream>>>(topk_idx, topk_w, block_offset,
                                        pair_token, pair_expert, pair_score, token_pos);

  // fused gate+up (interleaved G/U): routed -> hr, shared -> hs
  gateup_fused<<<GU_BLKS, 512, 0, stream>>>(
      xb, WguT, hr, WsguT, hs, pair_token, pair_expert, meta);

  // fused down: routed -> rout (bf16, scaled) || shared -> out (fp32)
  down_fused<<<DN_BLKS, 512, 0, stream>>>(
      hr, WdT, rout, pair_score, pair_expert, meta, hs, WsdT, out);

  // coalesced combine: out[t] += rout[p0] + rout[p1]
  combine_kernel<<<T / 16, 256, 0, stream>>>(out, rout, token_pos);
}